// Round 1
// baseline (145.634 us; speedup 1.0000x reference)
//
#include <hip/hip_runtime.h>

#define NBATCH 16
#define NANCH  3
#define NGRID  64
#define NT     60
#define NPB    (NANCH*NGRID*NGRID)   // 12288 cells per batch
#define NCELL  (NBATCH*NPB)          // 196608 total cells
#define NLBL   (NBATCH*NT)           // 960 labels
#define FEPS   1e-16f

// double accumulator slots
enum { A_XY=0, A_WH, A_IG, A_PG, A_GG, A_HM, A_GOU2, A_IOU2, A_CONFB, A_GTGOU, A_GTIOU, A_NACC };

__device__ __forceinline__ float sigm(float x) { return 1.0f / (1.0f + expf(-x)); }

__device__ __forceinline__ float waveSum(float v) {
#pragma unroll
    for (int o = 32; o > 0; o >>= 1) v += __shfl_down(v, o, 64);
    return v;
}

// ---------------------------------------------------------------------------
// Kernel A: build_target label-wise. One block, 1024 threads, j<960 active.
// Computes occurrence index (occ) per label; labels with occ<3 own a unique
// cell (b,a,gj,gi). Sets obj bit; accumulates loss_xy/loss_wh numerators,
// ig = sum conf over obj cells, gg = cnt = number of obj cells.
// ---------------------------------------------------------------------------
__global__ __launch_bounds__(1024)
void kA_build_target(const float* __restrict__ labels, const float* __restrict__ out,
                     unsigned int* __restrict__ obj_bits, double* __restrict__ acc) {
    __shared__ int keys[NLBL];
    __shared__ float red[16];
    int j = threadIdx.x;

    int b = 0, gi = 0, gj = 0, key = 0;
    float bx = 0.f, by = 0.f, lw_ = 0.f, lh_ = 0.f;
    if (j < NLBL) {
        const float* lp = labels + j * 5;
        b = (int)lp[0];
        bx = lp[1] * (float)NGRID;
        by = lp[2] * (float)NGRID;
        lw_ = lp[3];
        lh_ = lp[4];
        gi = (int)bx;
        gj = (int)by;
        key = (b * NGRID + gj) * NGRID + gi;
        keys[j] = key;
    }
    __syncthreads();

    float sxy = 0.f, swh = 0.f, sig_ = 0.f, scnt = 0.f;
    if (j < NLBL) {
        int occ = 0;
        for (int i = 0; i < j; ++i)
            if (keys[i] == key) occ++;
        if (occ < NANCH) {
            int a = occ;
            int cell = ((b * NANCH + a) * NGRID + gj) * NGRID + gi;
            atomicOr(&obj_bits[cell >> 5], 1u << (cell & 31));
            int base = ((b * NANCH * 5 + a * 5) * NGRID + gj) * NGRID + gi;
            float xs = sigm(out[base]);
            float ys = sigm(out[base + NGRID * NGRID]);
            float ws = sigm(out[base + 2 * NGRID * NGRID]);
            float hs = sigm(out[base + 3 * NGRID * NGRID]);
            float cf = sigm(out[base + 4 * NGRID * NGRID]);
            float tx = bx - floorf(bx);
            float ty = by - floorf(by);
            float dx = xs - tx, dy = ys - ty;
            sxy = dx * dx + dy * dy;
            float dw = logf(ws) - logf(lw_);
            float dh = logf(hs) - logf(lh_);
            swh = dw * dw + dh * dh;
            sig_ = cf;
            scnt = 1.f;
        }
    }

    // block-reduce the 4 sums over 16 waves
    float vals[4] = { sxy, swh, sig_, scnt };
    int wave = threadIdx.x >> 6, lane = threadIdx.x & 63;
#pragma unroll
    for (int k = 0; k < 4; ++k) {
        float v = waveSum(vals[k]);
        if (lane == 0) red[wave] = v;
        __syncthreads();
        if (threadIdx.x == 0) {
            float r = 0.f;
            for (int w = 0; w < 16; ++w) r += red[w];
            vals[k] = r;
        }
        __syncthreads();
    }
    if (threadIdx.x == 0) {
        acc[A_XY] = (double)vals[0];
        acc[A_WH] = (double)vals[1];
        acc[A_IG] = (double)vals[2];
        acc[A_GG] = (double)vals[3];
    }
}

// ---------------------------------------------------------------------------
// Kernel B: per-cell. Sigmoid-decode box, loop 60 GTs, track max-gou (first
// index on ties via strict >) and iou at argmax. Store pd_gou/pd_iou/conf.
// Also accumulate pg = sum conf^2 over all cells.
// ---------------------------------------------------------------------------
__global__ __launch_bounds__(256)
void kB_main(const float* __restrict__ out, const float* __restrict__ labels,
             float* __restrict__ pd_gou, float* __restrict__ pd_iou,
             float* __restrict__ conf_ws, double* __restrict__ acc) {
    int idx = blockIdx.x * 256 + threadIdx.x;     // 0..NCELL-1
    int b = idx / NPB;                            // uniform per block (12288 % 256 == 0)
    int n = idx - b * NPB;

    __shared__ float G[NT][5];                    // gx1,gy1,gx2,gy2,area
    __shared__ float red[4];
    if (threadIdx.x < NT) {
        const float* lp = labels + (b * NT + threadIdx.x) * 5;
        float gx = lp[1], gy = lp[2], gw = lp[3], gh = lp[4];
        G[threadIdx.x][0] = gx - gw * 0.5f;
        G[threadIdx.x][1] = gy - gh * 0.5f;
        G[threadIdx.x][2] = gx + gw * 0.5f;
        G[threadIdx.x][3] = gy + gh * 0.5f;
        G[threadIdx.x][4] = gw * gh;
    }
    __syncthreads();

    int a = n >> 12, gj = (n >> 6) & 63, gi = n & 63;
    int base = ((b * NANCH * 5 + a * 5) * NGRID + gj) * NGRID + gi;
    float xs = sigm(out[base]);
    float ys = sigm(out[base + NGRID * NGRID]);
    float ws = sigm(out[base + 2 * NGRID * NGRID]);
    float hs = sigm(out[base + 3 * NGRID * NGRID]);
    float cf = sigm(out[base + 4 * NGRID * NGRID]);

    float bx = (xs + (float)gi) * (1.0f / NGRID);
    float by = (ys + (float)gj) * (1.0f / NGRID);
    float px1 = bx - ws * 0.5f, px2 = bx + ws * 0.5f;
    float py1 = by - hs * 0.5f, py2 = by + hs * 0.5f;
    float pa = ws * hs;

    float best = -1e30f, biou = 0.0f;
    for (int t = 0; t < NT; ++t) {
        float gx1 = G[t][0], gy1 = G[t][1], gx2 = G[t][2], gy2 = G[t][3], ga = G[t][4];
        float iw = fminf(px2, gx2) - fmaxf(px1, gx1); iw = fmaxf(iw, 0.f);
        float ih = fminf(py2, gy2) - fmaxf(py1, gy1); ih = fmaxf(ih, 0.f);
        float inter = iw * ih;
        float un = pa + ga - inter;
        float iou = inter / (un + FEPS);
        float cw = fmaxf(px2, gx2) - fminf(px1, gx1);
        float ch = fmaxf(py2, gy2) - fminf(py1, gy1);
        float ca = cw * ch;
        float gou = iou - (ca - un) / (ca + FEPS);
        if (gou > best) { best = gou; biou = iou; }
    }
    pd_gou[idx] = best;
    pd_iou[idx] = biou;
    conf_ws[idx] = cf;

    // pg = sum conf^2 (all cells)
    float v = waveSum(cf * cf);
    int wave = threadIdx.x >> 6, lane = threadIdx.x & 63;
    if (lane == 0) red[wave] = v;
    __syncthreads();
    if (threadIdx.x == 0)
        atomicAdd(&acc[A_PG], (double)(red[0] + red[1] + red[2] + red[3]));
}

// ---------------------------------------------------------------------------
// Kernel C: gt-side. One block per (b,t): max gou over n (first-index tie
// break), iou at argmax. Scatter winning n into mask_ bitmask; accumulate
// sum(1-gt_gou), sum(1-iou_best).
// ---------------------------------------------------------------------------
__global__ __launch_bounds__(256)
void kC_gtmax(const float* __restrict__ out, const float* __restrict__ labels,
              unsigned int* __restrict__ mask_bits, double* __restrict__ acc) {
    int bt = blockIdx.x;
    int b = bt / NT;
    const float* lp = labels + bt * 5;
    float gx = lp[1], gy = lp[2], gw = lp[3], gh = lp[4];
    float gx1 = gx - gw * 0.5f, gy1 = gy - gh * 0.5f;
    float gx2 = gx + gw * 0.5f, gy2 = gy + gh * 0.5f;
    float ga = gw * gh;

    float best = -1e30f, biou = 0.0f;
    int bidx = 0x7fffffff;
    for (int n = threadIdx.x; n < NPB; n += 256) {
        int a = n >> 12, gj = (n >> 6) & 63, gi = n & 63;
        int base = ((b * NANCH * 5 + a * 5) * NGRID + gj) * NGRID + gi;
        float xs = sigm(out[base]);
        float ys = sigm(out[base + NGRID * NGRID]);
        float ws = sigm(out[base + 2 * NGRID * NGRID]);
        float hs = sigm(out[base + 3 * NGRID * NGRID]);
        float bx = (xs + (float)gi) * (1.0f / NGRID);
        float by = (ys + (float)gj) * (1.0f / NGRID);
        float px1 = bx - ws * 0.5f, px2 = bx + ws * 0.5f;
        float py1 = by - hs * 0.5f, py2 = by + hs * 0.5f;
        float pa = ws * hs;
        float iw = fminf(px2, gx2) - fmaxf(px1, gx1); iw = fmaxf(iw, 0.f);
        float ih = fminf(py2, gy2) - fmaxf(py1, gy1); ih = fmaxf(ih, 0.f);
        float inter = iw * ih;
        float un = pa + ga - inter;
        float iou = inter / (un + FEPS);
        float cw = fmaxf(px2, gx2) - fminf(px1, gx1);
        float ch = fmaxf(py2, gy2) - fminf(py1, gy1);
        float ca = cw * ch;
        float gou = iou - (ca - un) / (ca + FEPS);
        if (gou > best) { best = gou; biou = iou; bidx = n; }  // strict >: keeps lowest n in-thread
    }

    // wave reduce with (max val, min idx) tie-break
#pragma unroll
    for (int o = 32; o > 0; o >>= 1) {
        float ov = __shfl_down(best, o, 64);
        float oiou = __shfl_down(biou, o, 64);
        int oi = __shfl_down(bidx, o, 64);
        if (ov > best || (ov == best && oi < bidx)) { best = ov; biou = oiou; bidx = oi; }
    }
    __shared__ float sv[4], siou[4];
    __shared__ int sidx[4];
    int wave = threadIdx.x >> 6, lane = threadIdx.x & 63;
    if (lane == 0) { sv[wave] = best; siou[wave] = biou; sidx[wave] = bidx; }
    __syncthreads();
    if (threadIdx.x == 0) {
        for (int w = 1; w < 4; ++w)
            if (sv[w] > best || (sv[w] == best && sidx[w] < bidx)) {
                best = sv[w]; biou = siou[w]; bidx = sidx[w];
            }
        int cell = b * NPB + bidx;
        atomicOr(&mask_bits[cell >> 5], 1u << (cell & 31));
        atomicAdd(&acc[A_GTGOU], (double)(1.0f - best));
        atomicAdd(&acc[A_GTIOU], (double)(1.0f - biou));
    }
}

// ---------------------------------------------------------------------------
// Kernel D: per-batch mask2/ignore/dice sums. 16 blocks.
// ---------------------------------------------------------------------------
__global__ __launch_bounds__(256)
void kD_batch(const float* __restrict__ pd_gou, const float* __restrict__ pd_iou,
              const float* __restrict__ conf_ws, const unsigned int* __restrict__ obj_bits,
              const unsigned int* __restrict__ mask_bits, double* __restrict__ acc) {
    int b = blockIdx.x;
    float c2 = 0.f, sg = 0.f, si = 0.f, sin_ = 0.f, spa = 0.f, sga = 0.f;
    for (int n = threadIdx.x; n < NPB; n += 256) {
        int idx = b * NPB + n;
        float pio = pd_iou[idx];
        float pgo = pd_gou[idx];
        float cf = conf_ws[idx];
        bool mk = (pio >= 0.5f);
        bool m_ = (mask_bits[idx >> 5] >> (idx & 31)) & 1u;
        bool ob = (obj_bits[idx >> 5] >> (idx & 31)) & 1u;
        float m2 = (mk || m_) ? 1.f : 0.f;
        float ign = (!mk || m_) ? 1.f : 0.f;
        float tc = (ob || m_) ? 1.f : 0.f;
        c2 += m2;
        sg += (1.f - pgo) * m2;
        si += (1.f - pio) * m2;
        sin_ += cf * tc * ign;
        spa += cf * cf * ign;
        sga += tc * ign;
    }
    float vals[6] = { c2, sg, si, sin_, spa, sga };
    __shared__ float red[4];
    int wave = threadIdx.x >> 6, lane = threadIdx.x & 63;
#pragma unroll
    for (int k = 0; k < 6; ++k) {
        float v = waveSum(vals[k]);
        if (lane == 0) red[wave] = v;
        __syncthreads();
        if (threadIdx.x == 0) vals[k] = red[0] + red[1] + red[2] + red[3];
        __syncthreads();
    }
    if (threadIdx.x == 0) {
        atomicAdd(&acc[A_GOU2], (double)(vals[1] / vals[0]));
        atomicAdd(&acc[A_IOU2], (double)(vals[2] / vals[0]));
        float confb = 1.0f - (2.0f * vals[3] + 1.0f) / (vals[4] + vals[5] + 1.0f);
        atomicAdd(&acc[A_CONFB], (double)confb);
    }
}

// ---------------------------------------------------------------------------
// Kernel E: heatmap MSE sum over 4*NCELL elements.
// ---------------------------------------------------------------------------
__global__ __launch_bounds__(256)
void kE_heatmap(const float* __restrict__ io, const float* __restrict__ hm,
                double* __restrict__ acc) {
    float s = 0.f;
    int stride = gridDim.x * blockDim.x;
    for (int i = blockIdx.x * blockDim.x + threadIdx.x; i < 4 * NCELL; i += stride) {
        float d = io[i] - hm[i];
        s += d * d;
    }
    __shared__ float red[4];
    float v = waveSum(s);
    int wave = threadIdx.x >> 6, lane = threadIdx.x & 63;
    if (lane == 0) red[wave] = v;
    __syncthreads();
    if (threadIdx.x == 0)
        atomicAdd(&acc[A_HM], (double)(red[0] + red[1] + red[2] + red[3]));
}

// ---------------------------------------------------------------------------
// Kernel F: finalize the 7 outputs.
// ---------------------------------------------------------------------------
__global__ void kF_final(const double* __restrict__ acc, float* __restrict__ outp) {
    if (threadIdx.x == 0 && blockIdx.x == 0) {
        double cnt = acc[A_GG];
        double lxy = acc[A_XY] / cnt;
        double lwh = acc[A_WH] / cnt;
        double lgou = acc[A_GTGOU] / (double)NLBL + acc[A_GOU2] / (double)NBATCH;
        double liou = acc[A_GTIOU] / (double)NLBL + acc[A_IOU2] / (double)NBATCH;
        double dice = (2.0 * acc[A_IG] + 1.0) / (acc[A_PG] + acc[A_GG] + 1.0);
        if (dice != dice) dice = 1.0;
        double lconf = 1.0 - dice + acc[A_CONFB] / (double)NBATCH;
        double total = lxy + lwh + lconf + lgou;
        double hmv = acc[A_HM] / (double)(4 * NCELL);
        outp[0] = (float)lxy;
        outp[1] = (float)lwh;
        outp[2] = (float)lconf;
        outp[3] = (float)liou;
        outp[4] = (float)lgou;
        outp[5] = (float)total;
        outp[6] = (float)hmv;
    }
}

// ---------------------------------------------------------------------------
extern "C" void kernel_launch(void* const* d_in, const int* in_sizes, int n_in,
                              void* d_out, int out_size, void* d_ws, size_t ws_size,
                              hipStream_t stream) {
    const float* out_p    = (const float*)d_in[0];
    const float* labels   = (const float*)d_in[1];
    const float* int_out  = (const float*)d_in[2];
    const float* heatmaps = (const float*)d_in[3];
    float* o = (float*)d_out;

    char* ws = (char*)d_ws;
    const size_t FB = (size_t)NCELL * sizeof(float);        // 786432 B
    float* pd_gou  = (float*)(ws);
    float* pd_iou  = (float*)(ws + FB);
    float* conf_ws = (float*)(ws + 2 * FB);
    unsigned int* obj_bits  = (unsigned int*)(ws + 3 * FB);              // 24576 B
    unsigned int* mask_bits = (unsigned int*)(ws + 3 * FB + NCELL / 8);  // 24576 B
    double* acc = (double*)(ws + 3 * FB + 2 * (NCELL / 8));
    size_t used = 3 * FB + 2 * (NCELL / 8) + 16 * sizeof(double);

    hipMemsetAsync(d_ws, 0, used, stream);
    hipLaunchKernelGGL(kA_build_target, dim3(1), dim3(1024), 0, stream, labels, out_p, obj_bits, acc);
    hipLaunchKernelGGL(kB_main, dim3(NCELL / 256), dim3(256), 0, stream, out_p, labels, pd_gou, pd_iou, conf_ws, acc);
    hipLaunchKernelGGL(kC_gtmax, dim3(NLBL), dim3(256), 0, stream, out_p, labels, mask_bits, acc);
    hipLaunchKernelGGL(kD_batch, dim3(NBATCH), dim3(256), 0, stream, pd_gou, pd_iou, conf_ws, obj_bits, mask_bits, acc);
    hipLaunchKernelGGL(kE_heatmap, dim3(512), dim3(256), 0, stream, int_out, heatmaps, acc);
    hipLaunchKernelGGL(kF_final, dim3(1), dim3(64), 0, stream, acc, o);
}

// Round 2
// 104.363 us; speedup vs baseline: 1.3955x; 1.3955x over previous
//
#include <hip/hip_runtime.h>

#define NBATCH 16
#define NANCH  3
#define NGRID  64
#define NT     60
#define NPB    (NANCH*NGRID*NGRID)   // 12288 cells per batch
#define NCELL  (NBATCH*NPB)          // 196608 total cells
#define NLBL   (NBATCH*NT)           // 960 labels
#define FEPS   1e-16f

// double accumulator slots
enum { A_XY=0, A_WH, A_IG, A_PG, A_GG, A_HM, A_GOU2, A_IOU2, A_CONFB, A_GTGOU, A_GTIOU, A_NACC };

__device__ __forceinline__ float sigm(float x) { return 1.0f / (1.0f + expf(-x)); }

__device__ __forceinline__ float waveSum(float v) {
#pragma unroll
    for (int o = 32; o > 0; o >>= 1) v += __shfl_down(v, o, 64);
    return v;
}

// monotone bijection float -> u32 (order-preserving); inverse below
__device__ __forceinline__ unsigned int ford(float f) {
    unsigned int u = __float_as_uint(f);
    return (u & 0x80000000u) ? ~u : (u | 0x80000000u);
}
__device__ __forceinline__ float ford_inv(unsigned int u) {
    unsigned int v = (u & 0x80000000u) ? (u & 0x7fffffffu) : ~u;
    return __uint_as_float(v);
}

// ---------------------------------------------------------------------------
// Kernel A: build_target label-wise. One block, 1024 threads, j<960 active.
// ---------------------------------------------------------------------------
__global__ __launch_bounds__(1024)
void kA_build_target(const float* __restrict__ labels, const float* __restrict__ out,
                     unsigned int* __restrict__ obj_bits, double* __restrict__ acc) {
    __shared__ int keys[NLBL];
    __shared__ float red[16];
    int j = threadIdx.x;

    int b = 0, gi = 0, gj = 0, key = 0;
    float bx = 0.f, by = 0.f, lw_ = 0.f, lh_ = 0.f;
    if (j < NLBL) {
        const float* lp = labels + j * 5;
        b = (int)lp[0];
        bx = lp[1] * (float)NGRID;
        by = lp[2] * (float)NGRID;
        lw_ = lp[3];
        lh_ = lp[4];
        gi = (int)bx;
        gj = (int)by;
        key = (b * NGRID + gj) * NGRID + gi;
        keys[j] = key;
    }
    __syncthreads();

    float sxy = 0.f, swh = 0.f, sig_ = 0.f, scnt = 0.f;
    if (j < NLBL) {
        int occ = 0;
        for (int i = 0; i < j; ++i)
            if (keys[i] == key) occ++;
        if (occ < NANCH) {
            int a = occ;
            int cell = ((b * NANCH + a) * NGRID + gj) * NGRID + gi;
            atomicOr(&obj_bits[cell >> 5], 1u << (cell & 31));
            int base = ((b * NANCH * 5 + a * 5) * NGRID + gj) * NGRID + gi;
            float xs = sigm(out[base]);
            float ys = sigm(out[base + NGRID * NGRID]);
            float ws = sigm(out[base + 2 * NGRID * NGRID]);
            float hs = sigm(out[base + 3 * NGRID * NGRID]);
            float cf = sigm(out[base + 4 * NGRID * NGRID]);
            float tx = bx - floorf(bx);
            float ty = by - floorf(by);
            float dx = xs - tx, dy = ys - ty;
            sxy = dx * dx + dy * dy;
            float dw = logf(ws) - logf(lw_);
            float dh = logf(hs) - logf(lh_);
            swh = dw * dw + dh * dh;
            sig_ = cf;
            scnt = 1.f;
        }
    }

    float vals[4] = { sxy, swh, sig_, scnt };
    int wave = threadIdx.x >> 6, lane = threadIdx.x & 63;
#pragma unroll
    for (int k = 0; k < 4; ++k) {
        float v = waveSum(vals[k]);
        if (lane == 0) red[wave] = v;
        __syncthreads();
        if (threadIdx.x == 0) {
            float r = 0.f;
            for (int w = 0; w < 16; ++w) r += red[w];
            vals[k] = r;
        }
        __syncthreads();
    }
    if (threadIdx.x == 0) {
        acc[A_XY] = (double)vals[0];
        acc[A_WH] = (double)vals[1];
        acc[A_IG] = (double)vals[2];
        acc[A_GG] = (double)vals[3];
    }
}

// ---------------------------------------------------------------------------
// Kernel B (fused): per-cell decode + pd-side max over GTs AND gt-side
// (max, first-argmax) over cells via packed-u64 wave reduce + atomicMax.
// ---------------------------------------------------------------------------
__global__ __launch_bounds__(256)
void kB_main(const float* __restrict__ out, const float* __restrict__ labels,
             float* __restrict__ pd_gou, float* __restrict__ pd_iou,
             float* __restrict__ conf_ws, unsigned long long* __restrict__ gtbest,
             double* __restrict__ acc) {
    int idx = blockIdx.x * 256 + threadIdx.x;     // 0..NCELL-1
    int b = blockIdx.x / (NPB / 256);             // 48 blocks per batch
    int n = idx - b * NPB;

    __shared__ float G[NT][5];                    // gx1,gy1,gx2,gy2,area
    __shared__ unsigned long long W[4][NT];       // per-wave gt-side winners
    __shared__ float red[4];
    if (threadIdx.x < NT) {
        const float* lp = labels + (b * NT + threadIdx.x) * 5;
        float gx = lp[1], gy = lp[2], gw = lp[3], gh = lp[4];
        G[threadIdx.x][0] = gx - gw * 0.5f;
        G[threadIdx.x][1] = gy - gh * 0.5f;
        G[threadIdx.x][2] = gx + gw * 0.5f;
        G[threadIdx.x][3] = gy + gh * 0.5f;
        G[threadIdx.x][4] = gw * gh;
    }
    __syncthreads();

    int a = n >> 12, gj = (n >> 6) & 63, gi = n & 63;
    int base = ((b * NANCH * 5 + a * 5) * NGRID + gj) * NGRID + gi;
    float xs = sigm(out[base]);
    float ys = sigm(out[base + NGRID * NGRID]);
    float ws = sigm(out[base + 2 * NGRID * NGRID]);
    float hs = sigm(out[base + 3 * NGRID * NGRID]);
    float cf = sigm(out[base + 4 * NGRID * NGRID]);

    float bx = (xs + (float)gi) * (1.0f / NGRID);
    float by = (ys + (float)gj) * (1.0f / NGRID);
    float px1 = bx - ws * 0.5f, px2 = bx + ws * 0.5f;
    float py1 = by - hs * 0.5f, py2 = by + hs * 0.5f;
    float pa = ws * hs;

    int wave = threadIdx.x >> 6, lane = threadIdx.x & 63;
    unsigned int invn = 0xFFFFFFFFu - (unsigned int)n;

    float best = -1e30f, biou = 0.0f;
    for (int t = 0; t < NT; ++t) {
        float gx1 = G[t][0], gy1 = G[t][1], gx2 = G[t][2], gy2 = G[t][3], ga = G[t][4];
        float iw = fminf(px2, gx2) - fmaxf(px1, gx1); iw = fmaxf(iw, 0.f);
        float ih = fminf(py2, gy2) - fmaxf(py1, gy1); ih = fmaxf(ih, 0.f);
        float inter = iw * ih;
        float un = pa + ga - inter;
        float iou = inter / (un + FEPS);
        float cw = fmaxf(px2, gx2) - fminf(px1, gx1);
        float ch = fmaxf(py2, gy2) - fminf(py1, gy1);
        float ca = cw * ch;
        float gou = iou - (ca - un) / (ca + FEPS);
        if (gou > best) { best = gou; biou = iou; }   // pd-side: first t on ties

        // gt-side: packed (gou desc, n asc) wave reduce
        unsigned long long pk = ((unsigned long long)ford(gou) << 32) | invn;
#pragma unroll
        for (int o = 32; o > 0; o >>= 1) {
            unsigned long long opk = __shfl_down(pk, o, 64);
            if (opk > pk) pk = opk;
        }
        if (lane == 0) W[wave][t] = pk;
    }
    pd_gou[idx] = best;
    pd_iou[idx] = biou;
    conf_ws[idx] = cf;

    __syncthreads();
    if (threadIdx.x < NT) {
        unsigned long long m = W[0][threadIdx.x];
        if (W[1][threadIdx.x] > m) m = W[1][threadIdx.x];
        if (W[2][threadIdx.x] > m) m = W[2][threadIdx.x];
        if (W[3][threadIdx.x] > m) m = W[3][threadIdx.x];
        atomicMax(&gtbest[b * NT + threadIdx.x], m);
    }

    // pg = sum conf^2 (all cells)
    float v = waveSum(cf * cf);
    if (lane == 0) red[wave] = v;
    __syncthreads();
    if (threadIdx.x == 0)
        atomicAdd(&acc[A_PG], (double)(red[0] + red[1] + red[2] + red[3]));
}

// ---------------------------------------------------------------------------
// Kernel C2: unpack 960 gt-side winners; set mask_ bit; recompute iou at the
// winning cell; accumulate sum(1-gt_gou), sum(1-iou_best). One block.
// ---------------------------------------------------------------------------
__global__ __launch_bounds__(1024)
void kC2_unpack(const float* __restrict__ out, const float* __restrict__ labels,
                const unsigned long long* __restrict__ gtbest,
                unsigned int* __restrict__ mask_bits, double* __restrict__ acc) {
    __shared__ float red[16];
    int j = threadIdx.x;
    float sgou = 0.f, siou = 0.f;
    if (j < NLBL) {
        int b = j / NT;
        unsigned long long pk = gtbest[j];
        float gou = ford_inv((unsigned int)(pk >> 32));
        int n = (int)(0xFFFFFFFFu - (unsigned int)(pk & 0xFFFFFFFFu));
        int cell = b * NPB + n;
        atomicOr(&mask_bits[cell >> 5], 1u << (cell & 31));

        // recompute iou at winning cell vs gt j
        int a = n >> 12, gj = (n >> 6) & 63, gi = n & 63;
        int base = ((b * NANCH * 5 + a * 5) * NGRID + gj) * NGRID + gi;
        float xs = sigm(out[base]);
        float ys = sigm(out[base + NGRID * NGRID]);
        float ws = sigm(out[base + 2 * NGRID * NGRID]);
        float hs = sigm(out[base + 3 * NGRID * NGRID]);
        float bx = (xs + (float)gi) * (1.0f / NGRID);
        float by = (ys + (float)gj) * (1.0f / NGRID);
        float px1 = bx - ws * 0.5f, px2 = bx + ws * 0.5f;
        float py1 = by - hs * 0.5f, py2 = by + hs * 0.5f;
        float pa = ws * hs;
        const float* lp = labels + j * 5;
        float gx = lp[1], gy = lp[2], gw = lp[3], gh = lp[4];
        float gx1 = gx - gw * 0.5f, gy1 = gy - gh * 0.5f;
        float gx2 = gx + gw * 0.5f, gy2 = gy + gh * 0.5f;
        float ga = gw * gh;
        float iw = fminf(px2, gx2) - fmaxf(px1, gx1); iw = fmaxf(iw, 0.f);
        float ih = fminf(py2, gy2) - fmaxf(py1, gy1); ih = fmaxf(ih, 0.f);
        float inter = iw * ih;
        float un = pa + ga - inter;
        float iou = inter / (un + FEPS);
        sgou = 1.f - gou;
        siou = 1.f - iou;
    }

    float vals[2] = { sgou, siou };
    int wave = threadIdx.x >> 6, lane = threadIdx.x & 63;
#pragma unroll
    for (int k = 0; k < 2; ++k) {
        float v = waveSum(vals[k]);
        if (lane == 0) red[wave] = v;
        __syncthreads();
        if (threadIdx.x == 0) {
            float r = 0.f;
            for (int w = 0; w < 16; ++w) r += red[w];
            vals[k] = r;
        }
        __syncthreads();
    }
    if (threadIdx.x == 0) {
        acc[A_GTGOU] = (double)vals[0];
        acc[A_GTIOU] = (double)vals[1];
    }
}

// ---------------------------------------------------------------------------
// Kernel D: per-batch mask2/ignore/dice sums. 16 blocks.
// ---------------------------------------------------------------------------
__global__ __launch_bounds__(256)
void kD_batch(const float* __restrict__ pd_gou, const float* __restrict__ pd_iou,
              const float* __restrict__ conf_ws, const unsigned int* __restrict__ obj_bits,
              const unsigned int* __restrict__ mask_bits, double* __restrict__ acc) {
    int b = blockIdx.x;
    float c2 = 0.f, sg = 0.f, si = 0.f, sin_ = 0.f, spa = 0.f, sga = 0.f;
    for (int n = threadIdx.x; n < NPB; n += 256) {
        int idx = b * NPB + n;
        float pio = pd_iou[idx];
        float pgo = pd_gou[idx];
        float cf = conf_ws[idx];
        bool mk = (pio >= 0.5f);
        bool m_ = (mask_bits[idx >> 5] >> (idx & 31)) & 1u;
        bool ob = (obj_bits[idx >> 5] >> (idx & 31)) & 1u;
        float m2 = (mk || m_) ? 1.f : 0.f;
        float ign = (!mk || m_) ? 1.f : 0.f;
        float tc = (ob || m_) ? 1.f : 0.f;
        c2 += m2;
        sg += (1.f - pgo) * m2;
        si += (1.f - pio) * m2;
        sin_ += cf * tc * ign;
        spa += cf * cf * ign;
        sga += tc * ign;
    }
    float vals[6] = { c2, sg, si, sin_, spa, sga };
    __shared__ float red[4];
    int wave = threadIdx.x >> 6, lane = threadIdx.x & 63;
#pragma unroll
    for (int k = 0; k < 6; ++k) {
        float v = waveSum(vals[k]);
        if (lane == 0) red[wave] = v;
        __syncthreads();
        if (threadIdx.x == 0) vals[k] = red[0] + red[1] + red[2] + red[3];
        __syncthreads();
    }
    if (threadIdx.x == 0) {
        atomicAdd(&acc[A_GOU2], (double)(vals[1] / vals[0]));
        atomicAdd(&acc[A_IOU2], (double)(vals[2] / vals[0]));
        float confb = 1.0f - (2.0f * vals[3] + 1.0f) / (vals[4] + vals[5] + 1.0f);
        atomicAdd(&acc[A_CONFB], (double)confb);
    }
}

// ---------------------------------------------------------------------------
// Kernel E: heatmap MSE sum over 4*NCELL elements, float4 loads.
// ---------------------------------------------------------------------------
__global__ __launch_bounds__(256)
void kE_heatmap(const float4* __restrict__ io, const float4* __restrict__ hm,
                double* __restrict__ acc) {
    float s = 0.f;
    int stride = gridDim.x * blockDim.x;
    for (int i = blockIdx.x * blockDim.x + threadIdx.x; i < NCELL; i += stride) {
        float4 a = io[i], b = hm[i];
        float d0 = a.x - b.x, d1 = a.y - b.y, d2 = a.z - b.z, d3 = a.w - b.w;
        s += d0 * d0 + d1 * d1 + d2 * d2 + d3 * d3;
    }
    __shared__ float red[4];
    float v = waveSum(s);
    int wave = threadIdx.x >> 6, lane = threadIdx.x & 63;
    if (lane == 0) red[wave] = v;
    __syncthreads();
    if (threadIdx.x == 0)
        atomicAdd(&acc[A_HM], (double)(red[0] + red[1] + red[2] + red[3]));
}

// ---------------------------------------------------------------------------
// Kernel F: finalize the 7 outputs.
// ---------------------------------------------------------------------------
__global__ void kF_final(const double* __restrict__ acc, float* __restrict__ outp) {
    if (threadIdx.x == 0 && blockIdx.x == 0) {
        double cnt = acc[A_GG];
        double lxy = acc[A_XY] / cnt;
        double lwh = acc[A_WH] / cnt;
        double lgou = acc[A_GTGOU] / (double)NLBL + acc[A_GOU2] / (double)NBATCH;
        double liou = acc[A_GTIOU] / (double)NLBL + acc[A_IOU2] / (double)NBATCH;
        double dice = (2.0 * acc[A_IG] + 1.0) / (acc[A_PG] + acc[A_GG] + 1.0);
        if (dice != dice) dice = 1.0;
        double lconf = 1.0 - dice + acc[A_CONFB] / (double)NBATCH;
        double total = lxy + lwh + lconf + lgou;
        double hmv = acc[A_HM] / (double)(4 * NCELL);
        outp[0] = (float)lxy;
        outp[1] = (float)lwh;
        outp[2] = (float)lconf;
        outp[3] = (float)liou;
        outp[4] = (float)lgou;
        outp[5] = (float)total;
        outp[6] = (float)hmv;
    }
}

// ---------------------------------------------------------------------------
extern "C" void kernel_launch(void* const* d_in, const int* in_sizes, int n_in,
                              void* d_out, int out_size, void* d_ws, size_t ws_size,
                              hipStream_t stream) {
    const float* out_p    = (const float*)d_in[0];
    const float* labels   = (const float*)d_in[1];
    const float* int_out  = (const float*)d_in[2];
    const float* heatmaps = (const float*)d_in[3];
    float* o = (float*)d_out;

    char* ws = (char*)d_ws;
    const size_t FB = (size_t)NCELL * sizeof(float);        // 786432 B
    float* pd_gou  = (float*)(ws);
    float* pd_iou  = (float*)(ws + FB);
    float* conf_ws = (float*)(ws + 2 * FB);
    unsigned int* obj_bits  = (unsigned int*)(ws + 3 * FB);              // 24576 B
    unsigned int* mask_bits = (unsigned int*)(ws + 3 * FB + NCELL / 8);  // 24576 B
    double* acc = (double*)(ws + 3 * FB + 2 * (NCELL / 8));              // 16 doubles
    unsigned long long* gtbest =
        (unsigned long long*)(ws + 3 * FB + 2 * (NCELL / 8) + 16 * sizeof(double));
    size_t used = 3 * FB + 2 * (NCELL / 8) + 16 * sizeof(double)
                + (size_t)NLBL * sizeof(unsigned long long);

    hipMemsetAsync(d_ws, 0, used, stream);
    hipLaunchKernelGGL(kA_build_target, dim3(1), dim3(1024), 0, stream, labels, out_p, obj_bits, acc);
    hipLaunchKernelGGL(kB_main, dim3(NCELL / 256), dim3(256), 0, stream, out_p, labels,
                       pd_gou, pd_iou, conf_ws, gtbest, acc);
    hipLaunchKernelGGL(kC2_unpack, dim3(1), dim3(1024), 0, stream, out_p, labels, gtbest, mask_bits, acc);
    hipLaunchKernelGGL(kD_batch, dim3(NBATCH), dim3(256), 0, stream, pd_gou, pd_iou, conf_ws,
                       obj_bits, mask_bits, acc);
    hipLaunchKernelGGL(kE_heatmap, dim3(512), dim3(256), 0, stream,
                       (const float4*)int_out, (const float4*)heatmaps, acc);
    hipLaunchKernelGGL(kF_final, dim3(1), dim3(64), 0, stream, acc, o);
}